// Round 1
// baseline (91.759 us; speedup 1.0000x reference)
//
#include <hip/hip_runtime.h>
#include <hip/hip_bf16.h>

// LinearAttention_41798621725051 on MI355X.
// Key identity: (qk * v_h) / qk == v_h elementwise (qk strictly positive,
// finite for these input stats), so the reference reduces to
//   out[s,b,:] = cumsum_b ( v[s,b,:] @ Wv^T )
// One bf16-MFMA GEMM (M=16384, N=1024, K=1024) with the batch-cumsum done
// as a free in-register prefix in the epilogue (C/D layout gives each lane
// 4 consecutive rows = the 4 batch entries of one s).

typedef short s16x8 __attribute__((ext_vector_type(8)));
typedef float f32x4 __attribute__((ext_vector_type(4)));

static __device__ __forceinline__ unsigned short f2bf(float x) {
  __hip_bfloat16 h = __float2bfloat16(x);
  return __builtin_bit_cast(unsigned short, h);
}

constexpr int S_ = 4096, B_ = 4, D_ = 1024;
constexpr int M_ = S_ * B_;   // 16384 rows (s*4 + b)
constexpr int N_ = D_;        // 1024
constexpr int K_ = D_;        // 1024
constexpr int BM = 128, BN = 128, BK = 32;

__global__ __launch_bounds__(256) void la_gemm_cumsum(
    const float* __restrict__ Vp,   // (M, K) row-major f32
    const float* __restrict__ Wp,   // (N, K) row-major f32 (Wv; B^T layout)
    float* __restrict__ out)        // (M, N) f32
{
  // 8 KB each, bf16 tiles; XOR-swizzled 16B chunks to kill bank conflicts.
  __shared__ __align__(16) unsigned short As[BM * BK];
  __shared__ __align__(16) unsigned short Bs[BN * BK];

  const int tid  = threadIdx.x;
  const int lane = tid & 63;
  const int wave = tid >> 6;
  const int wr = wave >> 1, wc = wave & 1;   // 2x2 wave grid, 64x64 out each
  const int mt = blockIdx.y, nt = blockIdx.x;

  f32x4 acc[4][4] = {};   // zero-init

  const float* Abase = Vp + (size_t)mt * BM * K_;
  const float* Bbase = Wp + (size_t)nt * BN * K_;

  for (int kt = 0; kt < K_ / BK; ++kt) {
    // ---- global loads (issued before barrier; overlap prior MFMA phase)
    float4 av[4], bv[4];
#pragma unroll
    for (int i = 0; i < 4; ++i) {
      const int id = i * 256 + tid;          // 0..1023 float4 slots
      const int r  = id >> 3;                // 0..127 tile row
      const int c4 = id & 7;                 // float4 index within 32-wide row
      av[i] = *(const float4*)(Abase + (size_t)r * K_ + kt * BK + c4 * 4);
      bv[i] = *(const float4*)(Bbase + (size_t)r * K_ + kt * BK + c4 * 4);
    }
    __syncthreads();   // prior iteration's ds_reads complete before overwrite
    // ---- convert f32 -> bf16, swizzled ds_write_b64
#pragma unroll
    for (int i = 0; i < 4; ++i) {
      const int id = i * 256 + tid;
      const int r  = id >> 3;
      const int c4 = id & 7;
      // 16B chunk index = c4>>1; swizzle with (r>>1)&3; 8B half = c4&1
      const int byteoff = r * 64 + ((((c4 >> 1) ^ ((r >> 1) & 3)) << 4)) + ((c4 & 1) << 3);
      uint2 pa, pb;
      pa.x = (unsigned)f2bf(av[i].x) | ((unsigned)f2bf(av[i].y) << 16);
      pa.y = (unsigned)f2bf(av[i].z) | ((unsigned)f2bf(av[i].w) << 16);
      pb.x = (unsigned)f2bf(bv[i].x) | ((unsigned)f2bf(bv[i].y) << 16);
      pb.y = (unsigned)f2bf(bv[i].z) | ((unsigned)f2bf(bv[i].w) << 16);
      *(uint2*)((char*)As + byteoff) = pa;
      *(uint2*)((char*)Bs + byteoff) = pb;
    }
    __syncthreads();

    // ---- LDS -> fragments (ds_read_b128, swizzle-matched) + 16 MFMA
    s16x8 af[4], bf[4];
    const int chunk = lane >> 4;             // which 8-elem k-chunk this lane holds
#pragma unroll
    for (int m = 0; m < 4; ++m) {
      const int row = wr * 64 + m * 16 + (lane & 15);
      const int off = row * 64 + ((chunk ^ ((row >> 1) & 3)) << 4);
      af[m] = *(const s16x8*)((const char*)As + off);
    }
#pragma unroll
    for (int n = 0; n < 4; ++n) {
      const int row = wc * 64 + n * 16 + (lane & 15);
      const int off = row * 64 + ((chunk ^ ((row >> 1) & 3)) << 4);
      bf[n] = *(const s16x8*)((const char*)Bs + off);
    }
#pragma unroll
    for (int m = 0; m < 4; ++m)
#pragma unroll
      for (int n = 0; n < 4; ++n)
        acc[m][n] = __builtin_amdgcn_mfma_f32_16x16x32_bf16(af[m], bf[n], acc[m][n], 0, 0, 0);
  }

  // ---- epilogue: batch-cumsum is a prefix over the f32x4 (rows s*4+0..3)
#pragma unroll
  for (int m = 0; m < 4; ++m) {
    const int row0 = mt * BM + wr * 64 + m * 16 + ((lane >> 4) << 2);  // multiple of 4
#pragma unroll
    for (int n = 0; n < 4; ++n) {
      f32x4 a = acc[m][n];
      a.y += a.x;  a.z += a.y;  a.w += a.z;   // cumsum over b = row % 4
      const int col = nt * BN + wc * 64 + n * 16 + (lane & 15);
      out[(size_t)(row0 + 0) * N_ + col] = a.x;
      out[(size_t)(row0 + 1) * N_ + col] = a.y;
      out[(size_t)(row0 + 2) * N_ + col] = a.z;
      out[(size_t)(row0 + 3) * N_ + col] = a.w;
    }
  }
}

extern "C" void kernel_launch(void* const* d_in, const int* in_sizes, int n_in,
                              void* d_out, int out_size, void* d_ws, size_t ws_size,
                              hipStream_t stream) {
  // setup_inputs order: q, k, v, Wq, Wk, Wv — only v and Wv matter.
  const float* v  = (const float*)d_in[2];
  const float* Wv = (const float*)d_in[5];
  float* out = (float*)d_out;
  (void)d_ws; (void)ws_size; (void)in_sizes; (void)n_in; (void)out_size;

  dim3 grid(N_ / BN, M_ / BM);   // (8, 128) = 1024 blocks
  la_gemm_cumsum<<<grid, dim3(256), 0, stream>>>(v, Wv, out);
}

// Round 2
// 68.778 us; speedup vs baseline: 1.3341x; 1.3341x over previous
//
#include <hip/hip_runtime.h>
#include <hip/hip_bf16.h>

// LinearAttention_41798621725051 on MI355X.
// Identity: (qk * v_h) / qk == v_h elementwise (qk strictly positive, finite),
// so reference == cumsum_b( v @ Wv^T ). One bf16 MFMA GEMM (M=16384, N=K=1024)
// with the batch-cumsum free in the epilogue (C/D frag rows = 4 consecutive
// global rows = the 4 batch entries of one s).
//
// R2: XCD-affine block remap (A-strip L2 reuse), reg-prefetch software
// pipeline + single-barrier LDS double-buffer, v_cvt_pk_bf16_f32 packing.

typedef short s16x8 __attribute__((ext_vector_type(8)));
typedef float f32x4 __attribute__((ext_vector_type(4)));

constexpr int S_ = 4096, B_ = 4, D_ = 1024;
constexpr int M_ = S_ * B_;   // 16384
constexpr int N_ = D_;        // 1024
constexpr int K_ = D_;        // 1024
constexpr int BM = 128, BN = 128, BK = 32;
constexpr int KSTEPS = K_ / BK;   // 32

static __device__ __forceinline__ unsigned cvtpk(float lo, float hi) {
  unsigned r;
  asm("v_cvt_pk_bf16_f32 %0, %1, %2" : "=v"(r) : "v"(lo), "v"(hi));
  return r;
}

__global__ __launch_bounds__(256) void la_gemm_cumsum(
    const float* __restrict__ Vp,   // (M, K) f32
    const float* __restrict__ Wp,   // (N, K) f32 (Wv, B^T layout)
    float* __restrict__ out)        // (M, N) f32
{
  // double-buffered bf16 tiles, XOR-swizzled 16B chunks (R1: 0 bank conflicts)
  __shared__ __align__(16) unsigned short As[2][BM * BK];
  __shared__ __align__(16) unsigned short Bs[2][BN * BK];

  const int tid  = threadIdx.x;
  const int lane = tid & 63;
  const int wave = tid >> 6;
  const int wr = wave >> 1, wc = wave & 1;

  // XCD-affine remap: the 8 nt-blocks of one mt share an XCD's L2.
  // id%8 = XCD (round-robin assignment); 16 mt-groups per XCD.
  const int id = blockIdx.x;
  const int xcd = id & 7;
  const int t   = id >> 3;          // 0..127
  const int mt  = xcd * 16 + (t >> 3);
  const int nt  = t & 7;

  f32x4 acc[4][4] = {};

  const float* Abase = Vp + (size_t)mt * BM * K_;
  const float* Bbase = Wp + (size_t)nt * BN * K_;

  auto loadset = [&](float4 (&av)[4], float4 (&bv)[4], int kt) {
#pragma unroll
    for (int i = 0; i < 4; ++i) {
      const int sid = i * 256 + tid;
      const int r   = sid >> 3;
      const int c4  = sid & 7;
      av[i] = *(const float4*)(Abase + (size_t)r * K_ + kt * BK + c4 * 4);
      bv[i] = *(const float4*)(Bbase + (size_t)r * K_ + kt * BK + c4 * 4);
    }
  };

  auto cvtwrite = [&](float4 (&av)[4], float4 (&bv)[4], int buf) {
#pragma unroll
    for (int i = 0; i < 4; ++i) {
      const int sid = i * 256 + tid;
      const int r   = sid >> 3;
      const int c4  = sid & 7;
      const int byteoff = r * 64 + (((c4 >> 1) ^ ((r >> 1) & 3)) << 4) + ((c4 & 1) << 3);
      uint2 pa, pb;
      pa.x = cvtpk(av[i].x, av[i].y);
      pa.y = cvtpk(av[i].z, av[i].w);
      pb.x = cvtpk(bv[i].x, bv[i].y);
      pb.y = cvtpk(bv[i].z, bv[i].w);
      *(uint2*)((char*)As[buf] + byteoff) = pa;
      *(uint2*)((char*)Bs[buf] + byteoff) = pb;
    }
  };

  auto readmfma = [&](int buf) {
    s16x8 af[4], bf[4];
    const int chunk = lane >> 4;
#pragma unroll
    for (int m = 0; m < 4; ++m) {
      const int row = wr * 64 + m * 16 + (lane & 15);
      const int off = row * 64 + ((chunk ^ ((row >> 1) & 3)) << 4);
      af[m] = *(const s16x8*)((const char*)As[buf] + off);
    }
#pragma unroll
    for (int n = 0; n < 4; ++n) {
      const int row = wc * 64 + n * 16 + (lane & 15);
      const int off = row * 64 + ((chunk ^ ((row >> 1) & 3)) << 4);
      bf[n] = *(const s16x8*)((const char*)Bs[buf] + off);
    }
#pragma unroll
    for (int m = 0; m < 4; ++m)
#pragma unroll
      for (int n = 0; n < 4; ++n)
        acc[m][n] = __builtin_amdgcn_mfma_f32_16x16x32_bf16(af[m], bf[n], acc[m][n], 0, 0, 0);
  };

  // Software pipeline: two register sets (A/B names static — no runtime
  // indexing of float4 arrays, rule #20), one barrier per K-step.
  float4 avA[4], bvA[4], avB[4], bvB[4];
  loadset(avA, bvA, 0);
  for (int kt = 0; kt < KSTEPS; kt += 2) {
    loadset(avB, bvB, kt + 1);        // prefetch next (in flight across cvt+MFMA)
    cvtwrite(avA, bvA, 0);
    __syncthreads();
    readmfma(0);
    if (kt + 2 < KSTEPS) loadset(avA, bvA, kt + 2);
    cvtwrite(avB, bvB, 1);
    __syncthreads();
    readmfma(1);
  }

  // Epilogue: batch-cumsum = prefix over the f32x4 (rows s*4 + 0..3).
#pragma unroll
  for (int m = 0; m < 4; ++m) {
    const int row0 = mt * BM + wr * 64 + m * 16 + ((lane >> 4) << 2);
#pragma unroll
    for (int n = 0; n < 4; ++n) {
      f32x4 a = acc[m][n];
      a.y += a.x;  a.z += a.y;  a.w += a.z;
      const int col = nt * BN + wc * 64 + n * 16 + (lane & 15);
      __builtin_nontemporal_store(a.x, &out[(size_t)(row0 + 0) * N_ + col]);
      __builtin_nontemporal_store(a.y, &out[(size_t)(row0 + 1) * N_ + col]);
      __builtin_nontemporal_store(a.z, &out[(size_t)(row0 + 2) * N_ + col]);
      __builtin_nontemporal_store(a.w, &out[(size_t)(row0 + 3) * N_ + col]);
    }
  }
}

extern "C" void kernel_launch(void* const* d_in, const int* in_sizes, int n_in,
                              void* d_out, int out_size, void* d_ws, size_t ws_size,
                              hipStream_t stream) {
  // setup_inputs order: q, k, v, Wq, Wk, Wv — only v and Wv matter.
  const float* v  = (const float*)d_in[2];
  const float* Wv = (const float*)d_in[5];
  float* out = (float*)d_out;
  (void)d_ws; (void)ws_size; (void)in_sizes; (void)n_in; (void)out_size;

  la_gemm_cumsum<<<dim3((M_ / BM) * (N_ / BN)), dim3(256), 0, stream>>>(v, Wv, out);
}

// Round 3
// 50.251 us; speedup vs baseline: 1.8260x; 1.3687x over previous
//
#include <hip/hip_runtime.h>
#include <hip/hip_bf16.h>

// LinearAttention_41798621725051 on MI355X.
// Identity: (qk * v_h) / qk == v_h elementwise (qk strictly positive, finite),
// so reference == cumsum_b( v @ Wv^T ): one bf16 MFMA GEMM (M=16384, N=K=1024),
// batch-cumsum free in the epilogue (C/D frag rows = 4 batch entries of one s).
//
// R3: m201 geometry — 256x256 tile, BK=64, 8 waves (2x4), 128 KiB LDS dbuf,
// 1 block/CU (grid=256). Fused f32->bf16 reg-staging with T14 schedule
// (issue loads early, cvt+ds_write late), ONE barrier per K-tile, counted
// overlap via register dependencies, setprio around MFMA clusters.

typedef short s16x8 __attribute__((ext_vector_type(8)));
typedef float f32x4 __attribute__((ext_vector_type(4)));

constexpr int M_ = 16384, N_ = 1024, K_ = 1024;
constexpr int BM = 256, BN = 256, BK = 64;
constexpr int KT = K_ / BK;            // 16 K-tiles
constexpr int LDS_BUF = 65536;         // 32KB A + 32KB B per buffer
constexpr size_t LDS_TOTAL = 131072;

static __device__ __forceinline__ unsigned cvtpk(float lo, float hi) {
  unsigned r;
  asm("v_cvt_pk_bf16_f32 %0, %1, %2" : "=v"(r) : "v"(lo), "v"(hi));
  return r;
}

__global__ __launch_bounds__(512, 2) void la_gemm_cumsum(
    const float* __restrict__ Vp,   // (M, K) f32
    const float* __restrict__ Wp,   // (N, K) f32 (Wv, B^T layout)
    float* __restrict__ out)        // (M, N) f32
{
  extern __shared__ char lds[];     // [2][A 32KB | B 32KB]

  const int tid  = threadIdx.x;
  const int lane = tid & 63;
  const int wave = tid >> 6;
  const int wr = wave >> 2;         // 0..1  (128 rows each)
  const int wc = wave & 3;          // 0..3  (64 cols each)

  // XCD-affine: 4 nt-blocks of one mt share an XCD's L2 (A-strip reuse).
  const int gid = blockIdx.x;       // 0..255, gid%8 = XCD
  const int xcd = gid & 7;
  const int q   = gid >> 3;         // 0..31
  const int mt  = xcd * 8 + (q >> 2);   // 0..63
  const int nt  = q & 3;                // 0..3

  // ---- staging addressing (per-thread constants)
  const int srow   = tid >> 3;      // 0..63 (row within 64-row group)
  const int schunk = tid & 7;       // source 8-float chunk within BK=64
  const float* sAp = Vp + (size_t)(mt * 256 + srow) * K_ + schunk * 8;
  const float* sBp = Wp + (size_t)(nt * 256 + srow) * K_ + schunk * 8;
  // swizzled LDS write byte (iteration-invariant): chunk' = chunk ^ (row&7)
  const int wbyte = srow * 128 + ((schunk ^ (srow & 7)) << 4);

  // ---- fragment read bases (row&7 == lane&7 for all m/n/wr/wc offsets)
  const int basa0 = (wr * 128 + (lane & 15)) * 128 + (((lane >> 4) ^ (lane & 7)) << 4);
  const int basa1 = basa0 ^ 64;     // kk=1: chunk += 4  ->  chunk' ^= 4
  const int basb0 = (wc * 64 + (lane & 15)) * 128 + (((lane >> 4) ^ (lane & 7)) << 4);
  const int basb1 = basb0 ^ 64;

  f32x4 acc[8][4] = {};             // 128 VGPR accumulator (wave: 128x64 C)
  float4 sa[8], sb[8];              // 64 VGPR stage (fully unrolled indices)

  auto loadset = [&](int kt) {      // issue 16 float4 global loads (async)
#pragma unroll
    for (int i = 0; i < 4; ++i) {
      const float* pa = sAp + kt * 64 + i * (64 * K_);
      const float* pb = sBp + kt * 64 + i * (64 * K_);
      sa[2 * i]     = *(const float4*)pa;
      sa[2 * i + 1] = *(const float4*)(pa + 4);
      sb[2 * i]     = *(const float4*)pb;
      sb[2 * i + 1] = *(const float4*)(pb + 4);
    }
  };

  auto cvtwrite = [&](int buf) {    // f32 -> bf16 pack, swizzled ds_write_b128
    char* A = lds + buf * LDS_BUF;
    char* B = A + 32768;
#pragma unroll
    for (int i = 0; i < 4; ++i) {
      uint4 wa, wb;
      wa.x = cvtpk(sa[2*i].x,   sa[2*i].y);   wa.y = cvtpk(sa[2*i].z,   sa[2*i].w);
      wa.z = cvtpk(sa[2*i+1].x, sa[2*i+1].y); wa.w = cvtpk(sa[2*i+1].z, sa[2*i+1].w);
      wb.x = cvtpk(sb[2*i].x,   sb[2*i].y);   wb.y = cvtpk(sb[2*i].z,   sb[2*i].w);
      wb.z = cvtpk(sb[2*i+1].x, sb[2*i+1].y); wb.w = cvtpk(sb[2*i+1].z, sb[2*i+1].w);
      *(uint4*)(A + wbyte + i * 8192) = wa;
      *(uint4*)(B + wbyte + i * 8192) = wb;
    }
  };

  auto compute = [&](int buf) {     // 24 ds_read_b128 + 64 MFMA per wave
    const char* A = lds + buf * LDS_BUF;
    const char* B = A + 32768;
#pragma unroll
    for (int kk = 0; kk < 2; ++kk) {
      const int ba = kk ? basa1 : basa0;
      const int bb = kk ? basb1 : basb0;
      s16x8 bf[4];
#pragma unroll
      for (int n = 0; n < 4; ++n) bf[n] = *(const s16x8*)(B + bb + n * 2048);
#pragma unroll
      for (int mh = 0; mh < 2; ++mh) {
        s16x8 af[4];
#pragma unroll
        for (int m = 0; m < 4; ++m) af[m] = *(const s16x8*)(A + ba + (mh * 4 + m) * 2048);
        __builtin_amdgcn_s_setprio(1);
#pragma unroll
        for (int m = 0; m < 4; ++m)
#pragma unroll
          for (int n = 0; n < 4; ++n)
            acc[mh * 4 + m][n] =
                __builtin_amdgcn_mfma_f32_16x16x32_bf16(af[m], bf[n], acc[mh * 4 + m][n], 0, 0, 0);
        __builtin_amdgcn_s_setprio(0);
      }
    }
  };

  // ---- prologue: tile 0 into buf0
  loadset(0);
  cvtwrite(0);
  __syncthreads();

  // ---- main loop: ONE barrier per K-tile.
  // compute reads buf[cur]; staging writes buf[cur^1]; loads for kt+1 are in
  // flight across the whole MFMA phase (T14 issue-early / write-late).
  for (int kt = 0; kt < KT; ++kt) {
    const int cur = kt & 1;
    if (kt + 1 < KT) loadset(kt + 1);
    compute(cur);
    if (kt + 1 < KT) cvtwrite(cur ^ 1);
    __syncthreads();
  }

  // ---- epilogue: batch-cumsum = prefix over f32x4 (rows s*4 + 0..3)
#pragma unroll
  for (int m = 0; m < 8; ++m) {
    const int row0 = mt * 256 + wr * 128 + m * 16 + ((lane >> 4) << 2);
#pragma unroll
    for (int n = 0; n < 4; ++n) {
      f32x4 a = acc[m][n];
      a.y += a.x;  a.z += a.y;  a.w += a.z;
      const int col = nt * 256 + wc * 64 + n * 16 + (lane & 15);
      out[(size_t)(row0 + 0) * N_ + col] = a.x;
      out[(size_t)(row0 + 1) * N_ + col] = a.y;
      out[(size_t)(row0 + 2) * N_ + col] = a.z;
      out[(size_t)(row0 + 3) * N_ + col] = a.w;
    }
  }
}

extern "C" void kernel_launch(void* const* d_in, const int* in_sizes, int n_in,
                              void* d_out, int out_size, void* d_ws, size_t ws_size,
                              hipStream_t stream) {
  // setup_inputs order: q, k, v, Wq, Wk, Wv — only v and Wv matter.
  const float* v  = (const float*)d_in[2];
  const float* Wv = (const float*)d_in[5];
  float* out = (float*)d_out;
  (void)d_ws; (void)ws_size; (void)in_sizes; (void)n_in; (void)out_size;

  // 128 KiB dynamic LDS needs the opt-in attribute (idempotent, capture-safe).
  static int attr_done = 0;  // host-side; same value every call, deterministic
  hipFuncSetAttribute((const void*)la_gemm_cumsum,
                      hipFuncAttributeMaxDynamicSharedMemorySize, (int)LDS_TOTAL);
  (void)attr_done;

  la_gemm_cumsum<<<dim3(256), dim3(512), LDS_TOTAL, stream>>>(v, Wv, out);
}